// Round 6
// baseline (705.953 us; speedup 1.0000x reference)
//
#include <hip/hip_runtime.h>
#include <math.h>

#define NN 100000
#define BSZ 256                    // nodes per bucket
#define NB 391                     // ceil(NN/BSZ)
#define NB2 782                    // both halves
constexpr float MAXNORM_C = 0.996f;   // (1 - 4e-3)/sqrt(c), c=1
constexpr float MINNORM_C = 1e-15f;

// ---------- prep: quad-pack the 4 weight matrices ----------
// wq[m*4096 + kg*256 + li*16 + r*4 + c] = W_m[(li*4+r)*64 + kg*4 + c]
// i.e. per (kg, li): a 4x4 block, rows j=li*4+r, cols k=kg*4+c.
__global__ void prep_quad(const float* __restrict__ Wp, const float* __restrict__ Wpc,
                          const float* __restrict__ Wn, const float* __restrict__ Wnc,
                          float* __restrict__ wq) {
    int idx = blockIdx.x * 256 + threadIdx.x;   // 0..16383
    int c  = idx & 3;
    int r  = (idx >> 2) & 3;
    int li = (idx >> 4) & 15;
    int kg = (idx >> 8) & 15;
    int m  = idx >> 12;
    const float* W = (m == 0) ? Wp : (m == 1) ? Wpc : (m == 2) ? Wn : Wnc;
    wq[idx] = W[(li * 4 + r) * 64 + kg * 4 + c];
}

__device__ inline float wave_sum64(float v) {
    #pragma unroll
    for (int m = 32; m >= 1; m >>= 1) v += __shfl_xor(v, m, 64);
    return v;
}

// reduce across the 16-lane group (masks 1,2,4,8 stay in-group)
__device__ inline float qreduce(float v) {
    v += __shfl_xor(v, 1, 64);
    v += __shfl_xor(v, 2, 64);
    v += __shfl_xor(v, 4, 64);
    v += __shfl_xor(v, 8, 64);
    return v;
}

// ---------- prep: hyp_bias = proj(expmap0(b, c), c), plus its |.|^2 ----------
__global__ void prep_bias(const float* __restrict__ bp, const float* __restrict__ bn,
                          float* __restrict__ hb) {
    int l = threadIdx.x;   // one wave
    #pragma unroll
    for (int h = 0; h < 2; ++h) {
        float u = (h ? bn : bp)[l];
        float norm = fmaxf(sqrtf(wave_sum64(u * u)), MINNORM_C);
        float s = tanhf(norm) / norm;          // sqrt_c = 1
        float v = s * u;
        float vn = fmaxf(sqrtf(wave_sum64(v * v)), MINNORM_C);
        if (vn > MAXNORM_C) v *= MAXNORM_C / vn;
        float y2 = wave_sum64(v * v);
        hb[h * 65 + l] = v;
        if (l == 0) hb[h * 65 + 64] = y2;
    }
}

// ---------- bucket count: per-block LDS histogram -> global atomics ----------
__global__ __launch_bounds__(256) void bucket_count(
    const int* __restrict__ pei, int E1,
    const int* __restrict__ nei, int E2,
    int* __restrict__ gcnt) {
    __shared__ int h[NB2];
    int tid = threadIdx.x;
    for (int i = tid; i < NB2; i += 256) h[i] = 0;
    __syncthreads();
    int tot = E1 + E2;
    int base = blockIdx.x * 8192;
    #pragma unroll 4
    for (int k = 0; k < 32; ++k) {
        int idx = base + k * 256 + tid;
        if (idx < tot) {
            int half = idx >= E1;
            int e = idx - (half ? E1 : 0);
            const int* ei = half ? nei : pei;
            int E = half ? E2 : E1;
            int dst = ei[E + e];
            atomicAdd(&h[half * NB + (dst >> 8)], 1);
        }
    }
    __syncthreads();
    for (int i = tid; i < NB2; i += 256) {
        int c = h[i];
        if (c) atomicAdd(&gcnt[i], c);
    }
}

// ---------- exclusive scan of NB2 bucket counts (single block) ----------
__global__ void bucket_scan(const int* __restrict__ gcnt, int* __restrict__ goffs,
                            int* __restrict__ gcursor) {
    __shared__ int tmp[256];
    int tid = threadIdx.x;
    int base = tid * 4;
    int items[4];
    int s = 0;
    #pragma unroll
    for (int i = 0; i < 4; ++i) {
        items[i] = (base + i < NB2) ? gcnt[base + i] : 0;
        s += items[i];
    }
    tmp[tid] = s;
    __syncthreads();
    for (int off = 1; off < 256; off <<= 1) {
        int v = (tid >= off) ? tmp[tid - off] : 0;
        __syncthreads();
        tmp[tid] += v;
        __syncthreads();
    }
    int run = tmp[tid] - s;
    #pragma unroll
    for (int i = 0; i < 4; ++i) {
        if (base + i < NB2) { goffs[base + i] = run; gcursor[base + i] = run; }
        run += items[i];
    }
}

// ---------- bucket scatter: two-pass block aggregation, packed writes ----------
// packed edge = (src << 8) | (dst & 255)   (src < 2^17, fits 25 bits)
__global__ __launch_bounds__(256) void bucket_scatter(
    const int* __restrict__ pei, int E1,
    const int* __restrict__ nei, int E2,
    int* __restrict__ gcursor, int* __restrict__ packed) {
    __shared__ int h[NB2];
    __shared__ int hb[NB2];
    int tid = threadIdx.x;
    for (int i = tid; i < NB2; i += 256) h[i] = 0;
    __syncthreads();
    int tot = E1 + E2;
    int base = blockIdx.x * 8192;
    // pass A: histogram
    #pragma unroll 4
    for (int k = 0; k < 32; ++k) {
        int idx = base + k * 256 + tid;
        if (idx < tot) {
            int half = idx >= E1;
            int e = idx - (half ? E1 : 0);
            const int* ei = half ? nei : pei;
            int E = half ? E2 : E1;
            int dst = ei[E + e];
            atomicAdd(&h[half * NB + (dst >> 8)], 1);
        }
    }
    __syncthreads();
    // reserve chunks
    for (int i = tid; i < NB2; i += 256) {
        int c = h[i];
        hb[i] = c ? atomicAdd(&gcursor[i], c) : 0;
    }
    __syncthreads();
    for (int i = tid; i < NB2; i += 256) h[i] = 0;
    __syncthreads();
    // pass B: claim local rank, write packed
    #pragma unroll 4
    for (int k = 0; k < 32; ++k) {
        int idx = base + k * 256 + tid;
        if (idx < tot) {
            int half = idx >= E1;
            int e = idx - (half ? E1 : 0);
            const int* ei = half ? nei : pei;
            int E = half ? E2 : E1;
            int src = ei[e];
            int dst = ei[E + e];
            int b = half * NB + (dst >> 8);
            int r = atomicAdd(&h[b], 1);
            packed[hb[b] + r] = (src << 8) | (dst & 255);
        }
    }
}

// ---------- node sort: one block per bucket; sort edges to node order ----------
__global__ __launch_bounds__(256) void node_sort(
    const int* __restrict__ goffs, const int* __restrict__ gcnt,
    const int* __restrict__ packed,
    int* __restrict__ esrc, int* __restrict__ ndeg, int* __restrict__ noffs) {
    __shared__ int h[256];
    __shared__ int sc[256];
    int tid = threadIdx.x;
    int bucket = blockIdx.x;
    int start = goffs[bucket];
    int cnt = gcnt[bucket];
    h[tid] = 0;
    __syncthreads();
    for (int i = start + tid; i < start + cnt; i += 256)
        atomicAdd(&h[packed[i] & 255], 1);
    __syncthreads();
    int deg = h[tid];
    // exclusive scan of degrees
    sc[tid] = deg;
    __syncthreads();
    for (int off = 1; off < 256; off <<= 1) {
        int v = (tid >= off) ? sc[tid - off] : 0;
        __syncthreads();
        sc[tid] += v;
        __syncthreads();
    }
    int excl = sc[tid] - deg;
    int half = bucket >= NB;
    int node = (bucket - (half ? NB : 0)) * BSZ + tid;
    if (node < NN) {
        ndeg[half * NN + node] = deg;
        noffs[half * NN + node] = start + excl;
    }
    // reuse h as local cursor
    h[tid] = excl;
    __syncthreads();
    for (int i = start + tid; i < start + cnt; i += 256) {
        int p = packed[i];
        int r = atomicAdd(&h[p & 255], 1);
        esrc[start + r] = p >> 8;
    }
}

// ---------- gather: wave per node-half (high TLP), writes MEAN ----------
__global__ __launch_bounds__(256) void gather_kernel(
    const int* __restrict__ noffs, const int* __restrict__ ndeg,
    const int* __restrict__ esrc, const float* __restrict__ x,
    float* __restrict__ out) {
    int wid = (blockIdx.x * 256 + threadIdx.x) >> 6;   // node-half id, 0..2NN
    int lane = threadIdx.x & 63;
    if (wid >= 2 * NN) return;
    int half = wid >= NN;
    int node = wid - (half ? NN : 0);
    int start = noffs[wid];
    int deg = ndeg[wid];
    float acc = 0.f;
    for (int b = 0; b < deg; b += 64) {
        int n = min(64, deg - b);
        int s_l = (b + lane < deg) ? esrc[start + b + lane] : 0;
        int i = 0;
        for (; i + 4 <= n; i += 4) {
            int a0 = __shfl(s_l, i, 64), a1 = __shfl(s_l, i + 1, 64);
            int a2 = __shfl(s_l, i + 2, 64), a3 = __shfl(s_l, i + 3, 64);
            float v0 = x[a0 * 64 + lane], v1 = x[a1 * 64 + lane];
            float v2 = x[a2 * 64 + lane], v3 = x[a3 * 64 + lane];
            acc += (v0 + v1) + (v2 + v3);
        }
        for (; i < n; ++i) acc += x[__shfl(s_l, i, 64) * 64 + lane];
    }
    float m = acc / fmaxf((float)deg, 1.f);
    out[(size_t)node * 128 + half * 64 + lane] = m;
}

// ---------- quad hyperbolic linear: proj(mobius_matvec(W, v, c)) ----------
// 16 lanes per node; lane li owns outputs j = li*4..li*4+3. Only 4 acc floats
// per lane -> no per-lane arrays, no spill (R5: float[64] arrays went to
// scratch: VGPR=84, 390 MB spill traffic, finalize 180 us).
__device__ __attribute__((always_inline)) inline float4 quad_hyp(
        const float* __restrict__ vrow, const float* __restrict__ wq, int li) {
    float a0 = 0.f, a1 = 0.f, a2 = 0.f, a3 = 0.f;
    float vn2 = 0.f;
    #pragma unroll
    for (int kg = 0; kg < 16; ++kg) {
        float4 v4 = *(const float4*)(vrow + kg * 4);
        vn2 = fmaf(v4.x, v4.x, fmaf(v4.y, v4.y, fmaf(v4.z, v4.z, fmaf(v4.w, v4.w, vn2))));
        const float* wb = wq + (kg * 16 + li) * 16;
        float4 w0 = *(const float4*)(wb);
        float4 w1 = *(const float4*)(wb + 4);
        float4 w2 = *(const float4*)(wb + 8);
        float4 w3 = *(const float4*)(wb + 12);
        a0 = fmaf(w0.x, v4.x, fmaf(w0.y, v4.y, fmaf(w0.z, v4.z, fmaf(w0.w, v4.w, a0))));
        a1 = fmaf(w1.x, v4.x, fmaf(w1.y, v4.y, fmaf(w1.z, v4.z, fmaf(w1.w, v4.w, a1))));
        a2 = fmaf(w2.x, v4.x, fmaf(w2.y, v4.y, fmaf(w2.z, v4.z, fmaf(w2.w, v4.w, a2))));
        a3 = fmaf(w3.x, v4.x, fmaf(w3.y, v4.y, fmaf(w3.z, v4.z, fmaf(w3.w, v4.w, a3))));
    }
    float mn2 = qreduce(fmaf(a0, a0, fmaf(a1, a1, fmaf(a2, a2, a3 * a3))));
    float xnorm = fmaxf(sqrtf(vn2), MINNORM_C);
    float mnorm = fmaxf(sqrtf(mn2), MINNORM_C);
    float z = fminf(xnorm, 1.0f - 1e-7f);                   // artanh clip (z >= 0)
    float art = 0.5f * logf((1.0f + z) / (1.0f - z));
    float t = tanhf(mnorm / xnorm * art);
    float scale = (mn2 == 0.f) ? 0.f : (t / mnorm);         // zero_mx branch
    // proj: rn2 = scale^2 * mn2 (analytic — no second reduction)
    float rn2 = scale * scale * mn2;
    float rnorm = fmaxf(sqrtf(rn2), MINNORM_C);
    float f = (rnorm > MAXNORM_C) ? (MAXNORM_C / rnorm) : 1.0f;
    float sf = scale * f;
    return make_float4(a0 * sf, a1 * sf, a2 * sf, a3 * sf);
}

// ---------- finalize: 4 nodes per wave, 16 lanes/node, 4 outputs/lane ----------
__global__ __launch_bounds__(256) void finalize_kernel(
    const float* __restrict__ x,
    const float* __restrict__ wq,    // 4 quad-packed 64x64 matrices
    const float* __restrict__ hb,    // 2 x 65
    float* __restrict__ out) {
    int half = blockIdx.x & 1;                      // uniform
    int nb = blockIdx.x >> 1;                       // 0..6249 (100000/16 exact)
    int wave = threadIdx.x >> 6;
    int lane = threadIdx.x & 63;
    int g = lane >> 4;                              // node slot in wave
    int li = lane & 15;                             // output quad
    int node = nb * 16 + wave * 4 + g;              // < 100000 always

    const float* wqA = wq + (half * 2) * 4096;      // W_pos / W_neg
    const float* wqB = wqA + 4096;                  // W_pos_cc / W_neg_cc
    const float* hbh = hb + half * 65;
    float* op = out + (size_t)node * 128 + half * 64;

    // chain A: proj(mobius_matvec(W, agg))  (agg = mean, read from out-half)
    float4 resA = quad_hyp(op, wqA, li);

    // chain B: proj(mobius_matvec(W_cc, x))
    float4 resB = quad_hyp(x + (size_t)node * 64, wqB, li);

    // proj(mobius_add(resB, hyp_bias)), c=1
    float4 h4 = *(const float4*)(hbh + li * 4);
    float x2 = qreduce(fmaf(resB.x, resB.x, fmaf(resB.y, resB.y,
                       fmaf(resB.z, resB.z, resB.w * resB.w))));
    float xy = qreduce(fmaf(resB.x, h4.x, fmaf(resB.y, h4.y,
                       fmaf(resB.z, h4.z, resB.w * h4.w))));
    float y2 = hbh[64];
    float A = 1.f + 2.f * xy + y2;
    float B = 1.f - x2;
    float den = 1.f + 2.f * xy + x2 * y2;
    float dinv = 1.f / fmaxf(den, MINNORM_C);
    float r0 = (A * resB.x + B * h4.x) * dinv;
    float r1 = (A * resB.y + B * h4.y) * dinv;
    float r2 = (A * resB.z + B * h4.z) * dinv;
    float r3 = (A * resB.w + B * h4.w) * dinv;
    float rn2 = qreduce(fmaf(r0, r0, fmaf(r1, r1, fmaf(r2, r2, r3 * r3))));
    float rnorm = fmaxf(sqrtf(rn2), MINNORM_C);
    float f = (rnorm > MAXNORM_C) ? (MAXNORM_C / rnorm) : 1.0f;

    float4 s;
    s.x = resA.x + r0 * f;
    s.y = resA.y + r1 * f;
    s.z = resA.z + r2 * f;
    s.w = resA.w + r3 * f;
    *(float4*)(op + li * 4) = s;
}

extern "C" void kernel_launch(void* const* d_in, const int* in_sizes, int n_in,
                              void* d_out, int out_size, void* d_ws, size_t ws_size,
                              hipStream_t stream) {
    const float* x   = (const float*)d_in[0];
    const float* Wp  = (const float*)d_in[1];
    const float* Wpc = (const float*)d_in[2];
    const float* bp  = (const float*)d_in[3];
    const float* Wn  = (const float*)d_in[4];
    const float* Wnc = (const float*)d_in[5];
    const float* bn  = (const float*)d_in[6];
    const int* pei = (const int*)d_in[7];
    const int* nei = (const int*)d_in[8];
    float* out = (float*)d_out;

    int E1 = in_sizes[7] / 2;
    int E2 = in_sizes[8] / 2;
    int tot = E1 + E2;

    // ws layout (4-byte units):
    //   gcnt[NB2] | goffs[NB2] | gcursor[NB2] | pad | ndeg[2NN] | noffs[2NN]
    //   | hb[192] | wq[16384] | packed[tot] | esrc[tot]
    int*   gcnt    = (int*)d_ws;
    int*   goffs   = gcnt + NB2;
    int*   gcursor = goffs + NB2;
    int*   ndeg    = gcursor + NB2 + 2;          // align
    int*   noffs   = ndeg + 2 * NN;
    float* hbp     = (float*)(noffs + 2 * NN);
    float* wq      = hbp + 192;
    int*   packed  = (int*)(wq + 16384);
    int*   esrc    = packed + tot;

    hipMemsetAsync(gcnt, 0, NB2 * sizeof(int), stream);

    prep_quad<<<64, 256, 0, stream>>>(Wp, Wpc, Wn, Wnc, wq);
    prep_bias<<<1, 64, 0, stream>>>(bp, bn, hbp);

    int nblk = (tot + 8191) / 8192;    // 391
    bucket_count<<<nblk, 256, 0, stream>>>(pei, E1, nei, E2, gcnt);
    bucket_scan<<<1, 256, 0, stream>>>(gcnt, goffs, gcursor);
    bucket_scatter<<<nblk, 256, 0, stream>>>(pei, E1, nei, E2, gcursor, packed);
    node_sort<<<NB2, 256, 0, stream>>>(goffs, gcnt, packed, esrc, ndeg, noffs);

    gather_kernel<<<(2 * NN * 64 + 255) / 256, 256, 0, stream>>>(noffs, ndeg, esrc, x, out);

    finalize_kernel<<<2 * (NN / 16), 256, 0, stream>>>(x, wq, hbp, out);
}

// Round 7
// 515.901 us; speedup vs baseline: 1.3684x; 1.3684x over previous
//
#include <hip/hip_runtime.h>
#include <math.h>

#define NN 100000
#define BSZ 256                    // nodes per bucket
#define NB 391                     // ceil(NN/BSZ)
#define NB2 782                    // both halves
constexpr float MAXNORM_C = 0.996f;   // (1 - 4e-3)/sqrt(c), c=1
constexpr float MINNORM_C = 1e-15f;

// ---------- prep: quad-pack the 4 weight matrices ----------
// wq[m*4096 + kg*256 + li*16 + r*4 + c] = W_m[(li*4+r)*64 + kg*4 + c]
__global__ void prep_quad(const float* __restrict__ Wp, const float* __restrict__ Wpc,
                          const float* __restrict__ Wn, const float* __restrict__ Wnc,
                          float* __restrict__ wq) {
    int idx = blockIdx.x * 256 + threadIdx.x;   // 0..16383
    int c  = idx & 3;
    int r  = (idx >> 2) & 3;
    int li = (idx >> 4) & 15;
    int kg = (idx >> 8) & 15;
    int m  = idx >> 12;
    const float* W = (m == 0) ? Wp : (m == 1) ? Wpc : (m == 2) ? Wn : Wnc;
    wq[idx] = W[(li * 4 + r) * 64 + kg * 4 + c];
}

__device__ inline float wave_sum64(float v) {
    #pragma unroll
    for (int m = 32; m >= 1; m >>= 1) v += __shfl_xor(v, m, 64);
    return v;
}

// reduce across the 16-lane group (masks 1,2,4,8 stay in-group)
__device__ inline float qreduce(float v) {
    v += __shfl_xor(v, 1, 64);
    v += __shfl_xor(v, 2, 64);
    v += __shfl_xor(v, 4, 64);
    v += __shfl_xor(v, 8, 64);
    return v;
}

// ---------- prep: hyp_bias = proj(expmap0(b, c), c), plus its |.|^2 ----------
__global__ void prep_bias(const float* __restrict__ bp, const float* __restrict__ bn,
                          float* __restrict__ hb) {
    int l = threadIdx.x;   // one wave
    #pragma unroll
    for (int h = 0; h < 2; ++h) {
        float u = (h ? bn : bp)[l];
        float norm = fmaxf(sqrtf(wave_sum64(u * u)), MINNORM_C);
        float s = tanhf(norm) / norm;          // sqrt_c = 1
        float v = s * u;
        float vn = fmaxf(sqrtf(wave_sum64(v * v)), MINNORM_C);
        if (vn > MAXNORM_C) v *= MAXNORM_C / vn;
        float y2 = wave_sum64(v * v);
        hb[h * 65 + l] = v;
        if (l == 0) hb[h * 65 + 64] = y2;
    }
}

// ---------- bucket count: per-block LDS histogram -> global atomics ----------
__global__ __launch_bounds__(256) void bucket_count(
    const int* __restrict__ pei, int E1,
    const int* __restrict__ nei, int E2,
    int* __restrict__ gcnt) {
    __shared__ int h[NB2];
    int tid = threadIdx.x;
    for (int i = tid; i < NB2; i += 256) h[i] = 0;
    __syncthreads();
    int tot = E1 + E2;
    int base = blockIdx.x * 8192;
    #pragma unroll 4
    for (int k = 0; k < 32; ++k) {
        int idx = base + k * 256 + tid;
        if (idx < tot) {
            int half = idx >= E1;
            int e = idx - (half ? E1 : 0);
            const int* ei = half ? nei : pei;
            int E = half ? E2 : E1;
            int dst = ei[E + e];
            atomicAdd(&h[half * NB + (dst >> 8)], 1);
        }
    }
    __syncthreads();
    for (int i = tid; i < NB2; i += 256) {
        int c = h[i];
        if (c) atomicAdd(&gcnt[i], c);
    }
}

// ---------- exclusive scan of NB2 bucket counts (single block) ----------
__global__ void bucket_scan(const int* __restrict__ gcnt, int* __restrict__ goffs,
                            int* __restrict__ gcursor) {
    __shared__ int tmp[256];
    int tid = threadIdx.x;
    int base = tid * 4;
    int items[4];
    int s = 0;
    #pragma unroll
    for (int i = 0; i < 4; ++i) {
        items[i] = (base + i < NB2) ? gcnt[base + i] : 0;
        s += items[i];
    }
    tmp[tid] = s;
    __syncthreads();
    for (int off = 1; off < 256; off <<= 1) {
        int v = (tid >= off) ? tmp[tid - off] : 0;
        __syncthreads();
        tmp[tid] += v;
        __syncthreads();
    }
    int run = tmp[tid] - s;
    #pragma unroll
    for (int i = 0; i < 4; ++i) {
        if (base + i < NB2) { goffs[base + i] = run; gcursor[base + i] = run; }
        run += items[i];
    }
}

// ---------- bucket scatter: two-pass block aggregation, packed writes ----------
// packed edge = (src << 8) | (dst & 255)   (src < 2^17, fits 25 bits)
__global__ __launch_bounds__(256) void bucket_scatter(
    const int* __restrict__ pei, int E1,
    const int* __restrict__ nei, int E2,
    int* __restrict__ gcursor, int* __restrict__ packed) {
    __shared__ int h[NB2];
    __shared__ int hb[NB2];
    int tid = threadIdx.x;
    for (int i = tid; i < NB2; i += 256) h[i] = 0;
    __syncthreads();
    int tot = E1 + E2;
    int base = blockIdx.x * 8192;
    // pass A: histogram
    #pragma unroll 4
    for (int k = 0; k < 32; ++k) {
        int idx = base + k * 256 + tid;
        if (idx < tot) {
            int half = idx >= E1;
            int e = idx - (half ? E1 : 0);
            const int* ei = half ? nei : pei;
            int E = half ? E2 : E1;
            int dst = ei[E + e];
            atomicAdd(&h[half * NB + (dst >> 8)], 1);
        }
    }
    __syncthreads();
    // reserve chunks
    for (int i = tid; i < NB2; i += 256) {
        int c = h[i];
        hb[i] = c ? atomicAdd(&gcursor[i], c) : 0;
    }
    __syncthreads();
    for (int i = tid; i < NB2; i += 256) h[i] = 0;
    __syncthreads();
    // pass B: claim local rank, write packed
    #pragma unroll 4
    for (int k = 0; k < 32; ++k) {
        int idx = base + k * 256 + tid;
        if (idx < tot) {
            int half = idx >= E1;
            int e = idx - (half ? E1 : 0);
            const int* ei = half ? nei : pei;
            int E = half ? E2 : E1;
            int src = ei[e];
            int dst = ei[E + e];
            int b = half * NB + (dst >> 8);
            int r = atomicAdd(&h[b], 1);
            packed[hb[b] + r] = (src << 8) | (dst & 255);
        }
    }
}

// ---------- node sort: one block per bucket; sort edges to node order ----------
__global__ __launch_bounds__(256) void node_sort(
    const int* __restrict__ goffs, const int* __restrict__ gcnt,
    const int* __restrict__ packed,
    int* __restrict__ esrc, int* __restrict__ ndeg, int* __restrict__ noffs) {
    __shared__ int h[256];
    __shared__ int sc[256];
    int tid = threadIdx.x;
    int bucket = blockIdx.x;
    int start = goffs[bucket];
    int cnt = gcnt[bucket];
    h[tid] = 0;
    __syncthreads();
    for (int i = start + tid; i < start + cnt; i += 256)
        atomicAdd(&h[packed[i] & 255], 1);
    __syncthreads();
    int deg = h[tid];
    // exclusive scan of degrees
    sc[tid] = deg;
    __syncthreads();
    for (int off = 1; off < 256; off <<= 1) {
        int v = (tid >= off) ? sc[tid - off] : 0;
        __syncthreads();
        sc[tid] += v;
        __syncthreads();
    }
    int excl = sc[tid] - deg;
    int half = bucket >= NB;
    int node = (bucket - (half ? NB : 0)) * BSZ + tid;
    if (node < NN) {
        ndeg[half * NN + node] = deg;
        noffs[half * NN + node] = start + excl;
    }
    // reuse h as local cursor
    h[tid] = excl;
    __syncthreads();
    for (int i = start + tid; i < start + cnt; i += 256) {
        int p = packed[i];
        int r = atomicAdd(&h[p & 255], 1);
        esrc[start + r] = p >> 8;
    }
}

// ---------- gather: wave per node-half (high TLP), writes MEAN ----------
__global__ __launch_bounds__(256) void gather_kernel(
    const int* __restrict__ noffs, const int* __restrict__ ndeg,
    const int* __restrict__ esrc, const float* __restrict__ x,
    float* __restrict__ out) {
    int wid = (blockIdx.x * 256 + threadIdx.x) >> 6;   // node-half id, 0..2NN
    int lane = threadIdx.x & 63;
    if (wid >= 2 * NN) return;
    int half = wid >= NN;
    int node = wid - (half ? NN : 0);
    int start = noffs[wid];
    int deg = ndeg[wid];
    float acc = 0.f;
    for (int b = 0; b < deg; b += 64) {
        int n = min(64, deg - b);
        int s_l = (b + lane < deg) ? esrc[start + b + lane] : 0;
        int i = 0;
        for (; i + 4 <= n; i += 4) {
            int a0 = __shfl(s_l, i, 64), a1 = __shfl(s_l, i + 1, 64);
            int a2 = __shfl(s_l, i + 2, 64), a3 = __shfl(s_l, i + 3, 64);
            float v0 = x[a0 * 64 + lane], v1 = x[a1 * 64 + lane];
            float v2 = x[a2 * 64 + lane], v3 = x[a3 * 64 + lane];
            acc += (v0 + v1) + (v2 + v3);
        }
        for (; i < n; ++i) acc += x[__shfl(s_l, i, 64) * 64 + lane];
    }
    float m = acc / fmaxf((float)deg, 1.f);
    out[(size_t)node * 128 + half * 64 + lane] = m;
}

// ---------- quad hyperbolic linear, weights from LDS ----------
// 16 lanes per node; lane li owns outputs j = li*4..li*4+3. 4 acc floats/lane
// (R6 proved no spill). Weights via ds_read_b128: 16 distinct 16B addrs/instr
// (2-way bank alias = free), 4-way lane broadcast — off the vmem pipe, which
// was R6's bottleneck (8M global weight loads, VALUBusy 26%, 418 us).
__device__ __attribute__((always_inline)) inline float4 quad_hyp(
        const float* __restrict__ vrow, const float* wlds, int li) {
    float a0 = 0.f, a1 = 0.f, a2 = 0.f, a3 = 0.f;
    float vn2 = 0.f;
    #pragma unroll
    for (int kg = 0; kg < 16; ++kg) {
        float4 v4 = *(const float4*)(vrow + kg * 4);
        vn2 = fmaf(v4.x, v4.x, fmaf(v4.y, v4.y, fmaf(v4.z, v4.z, fmaf(v4.w, v4.w, vn2))));
        const float* wb = wlds + (kg * 16 + li) * 16;
        float4 w0 = *(const float4*)(wb);
        float4 w1 = *(const float4*)(wb + 4);
        float4 w2 = *(const float4*)(wb + 8);
        float4 w3 = *(const float4*)(wb + 12);
        a0 = fmaf(w0.x, v4.x, fmaf(w0.y, v4.y, fmaf(w0.z, v4.z, fmaf(w0.w, v4.w, a0))));
        a1 = fmaf(w1.x, v4.x, fmaf(w1.y, v4.y, fmaf(w1.z, v4.z, fmaf(w1.w, v4.w, a1))));
        a2 = fmaf(w2.x, v4.x, fmaf(w2.y, v4.y, fmaf(w2.z, v4.z, fmaf(w2.w, v4.w, a2))));
        a3 = fmaf(w3.x, v4.x, fmaf(w3.y, v4.y, fmaf(w3.z, v4.z, fmaf(w3.w, v4.w, a3))));
    }
    float mn2 = qreduce(fmaf(a0, a0, fmaf(a1, a1, fmaf(a2, a2, a3 * a3))));
    float xnorm = fmaxf(sqrtf(vn2), MINNORM_C);
    float mnorm = fmaxf(sqrtf(mn2), MINNORM_C);
    float z = fminf(xnorm, 1.0f - 1e-7f);                   // artanh clip (z >= 0)
    float art = 0.5f * logf((1.0f + z) / (1.0f - z));
    float t = tanhf(mnorm / xnorm * art);
    float scale = (mn2 == 0.f) ? 0.f : (t / mnorm);         // zero_mx branch
    float rn2 = scale * scale * mn2;                        // proj, analytic
    float rnorm = fmaxf(sqrtf(rn2), MINNORM_C);
    float f = (rnorm > MAXNORM_C) ? (MAXNORM_C / rnorm) : 1.0f;
    float sf = scale * f;
    return make_float4(a0 * sf, a1 * sf, a2 * sf, a3 * sf);
}

// ---------- finalize: 1024 thr, 64 nodes/block, weights staged in LDS ----------
__global__ __launch_bounds__(1024) void finalize_kernel(
    const float* __restrict__ x,
    const float* __restrict__ wq,    // 4 quad-packed 64x64 matrices
    const float* __restrict__ hb,    // 2 x 65
    float* __restrict__ out) {
    __shared__ float wl[8192];       // [0:4096)=W_half, [4096:8192)=W_half_cc
    int half = blockIdx.x & 1;                      // uniform
    int nb = blockIdx.x >> 1;

    {   // stage this half's two matrices (32 KB)
        const float4* ws4 = (const float4*)(wq + half * 2 * 4096);
        float4* wl4 = (float4*)wl;
        #pragma unroll
        for (int i = 0; i < 2; ++i)
            wl4[i * 1024 + threadIdx.x] = ws4[i * 1024 + threadIdx.x];
    }
    __syncthreads();

    int wave = threadIdx.x >> 6;
    int lane = threadIdx.x & 63;
    int g = lane >> 4;                              // node slot in wave
    int li = lane & 15;                             // output quad
    int node = nb * 64 + wave * 4 + g;
    bool valid = node < NN;
    int ncl = valid ? node : NN - 1;

    const float* hbh = hb + half * 65;
    float* op = out + (size_t)ncl * 128 + half * 64;

    // chain A: proj(mobius_matvec(W, agg))  (agg = mean, read from out-half)
    float4 resA = quad_hyp(op, wl, li);

    // chain B: proj(mobius_matvec(W_cc, x))
    float4 resB = quad_hyp(x + (size_t)ncl * 64, wl + 4096, li);

    // proj(mobius_add(resB, hyp_bias)), c=1
    float4 h4 = *(const float4*)(hbh + li * 4);
    float x2 = qreduce(fmaf(resB.x, resB.x, fmaf(resB.y, resB.y,
                       fmaf(resB.z, resB.z, resB.w * resB.w))));
    float xy = qreduce(fmaf(resB.x, h4.x, fmaf(resB.y, h4.y,
                       fmaf(resB.z, h4.z, resB.w * h4.w))));
    float y2 = hbh[64];
    float A = 1.f + 2.f * xy + y2;
    float B = 1.f - x2;
    float den = 1.f + 2.f * xy + x2 * y2;
    float dinv = 1.f / fmaxf(den, MINNORM_C);
    float r0 = (A * resB.x + B * h4.x) * dinv;
    float r1 = (A * resB.y + B * h4.y) * dinv;
    float r2 = (A * resB.z + B * h4.z) * dinv;
    float r3 = (A * resB.w + B * h4.w) * dinv;
    float rn2 = qreduce(fmaf(r0, r0, fmaf(r1, r1, fmaf(r2, r2, r3 * r3))));
    float rnorm = fmaxf(sqrtf(rn2), MINNORM_C);
    float f = (rnorm > MAXNORM_C) ? (MAXNORM_C / rnorm) : 1.0f;

    if (valid) {
        float4 s;
        s.x = resA.x + r0 * f;
        s.y = resA.y + r1 * f;
        s.z = resA.z + r2 * f;
        s.w = resA.w + r3 * f;
        *(float4*)(op + li * 4) = s;
    }
}

extern "C" void kernel_launch(void* const* d_in, const int* in_sizes, int n_in,
                              void* d_out, int out_size, void* d_ws, size_t ws_size,
                              hipStream_t stream) {
    const float* x   = (const float*)d_in[0];
    const float* Wp  = (const float*)d_in[1];
    const float* Wpc = (const float*)d_in[2];
    const float* bp  = (const float*)d_in[3];
    const float* Wn  = (const float*)d_in[4];
    const float* Wnc = (const float*)d_in[5];
    const float* bn  = (const float*)d_in[6];
    const int* pei = (const int*)d_in[7];
    const int* nei = (const int*)d_in[8];
    float* out = (float*)d_out;

    int E1 = in_sizes[7] / 2;
    int E2 = in_sizes[8] / 2;
    int tot = E1 + E2;

    // ws layout (4-byte units):
    //   gcnt[NB2] | goffs[NB2] | gcursor[NB2] | pad | ndeg[2NN] | noffs[2NN]
    //   | hb[192] | wq[16384] | packed[tot] | esrc[tot]
    int*   gcnt    = (int*)d_ws;
    int*   goffs   = gcnt + NB2;
    int*   gcursor = goffs + NB2;
    int*   ndeg    = gcursor + NB2 + 2;          // align
    int*   noffs   = ndeg + 2 * NN;
    float* hbp     = (float*)(noffs + 2 * NN);
    float* wq      = hbp + 192;
    int*   packed  = (int*)(wq + 16384);
    int*   esrc    = packed + tot;

    hipMemsetAsync(gcnt, 0, NB2 * sizeof(int), stream);

    prep_quad<<<64, 256, 0, stream>>>(Wp, Wpc, Wn, Wnc, wq);
    prep_bias<<<1, 64, 0, stream>>>(bp, bn, hbp);

    int nblk = (tot + 8191) / 8192;    // 391
    bucket_count<<<nblk, 256, 0, stream>>>(pei, E1, nei, E2, gcnt);
    bucket_scan<<<1, 256, 0, stream>>>(gcnt, goffs, gcursor);
    bucket_scatter<<<nblk, 256, 0, stream>>>(pei, E1, nei, E2, gcursor, packed);
    node_sort<<<NB2, 256, 0, stream>>>(goffs, gcnt, packed, esrc, ndeg, noffs);

    gather_kernel<<<(2 * NN * 64 + 255) / 256, 256, 0, stream>>>(noffs, ndeg, esrc, x, out);

    int nbf = (NN + 63) / 64;                    // 1563
    finalize_kernel<<<2 * nbf, 1024, 0, stream>>>(x, wq, hbp, out);
}